// Round 1
// baseline (196.883 us; speedup 1.0000x reference)
//
#include <hip/hip_runtime.h>

// Reference dataflow analysis:
//   step() returns (C_new, H0)  -> scan outputs = H0 tiled T times
//   reference returns (outputs, H0) -> C_final and all gate math are DEAD CODE
// So d_out = [H0 repeated T times][H0]  == H0 tiled (T+1)=513 times.
// Pure write-BW problem: 134.5 MB writes, 256 KB reads (cache-resident).

// B*H = 128*512 = 65536 floats = 16384 float4. Power of two -> mask.
#define SRC_MASK4 16383

__global__ void __launch_bounds__(256) tile_h0_kernel(
    const float4* __restrict__ h0, float4* __restrict__ out, int n4) {
  int i = blockIdx.x * blockDim.x + threadIdx.x;
  if (i < n4) {
    out[i] = h0[i & SRC_MASK4];
  }
}

extern "C" void kernel_launch(void* const* d_in, const int* in_sizes, int n_in,
                              void* d_out, int out_size, void* d_ws, size_t ws_size,
                              hipStream_t stream) {
  // Input order: inputs, H0, C0, W_xi, b_xi, W_hi, b_hi, ... (dict order)
  const float* H0 = (const float*)d_in[1];

  int n4 = out_size / 4;  // 33,619,968 / 4 = 8,404,992 float4 stores
  const int block = 256;
  int grid = (n4 + block - 1) / block;

  tile_h0_kernel<<<grid, block, 0, stream>>>(
      (const float4*)H0, (float4*)d_out, n4);
}